// Round 1
// baseline (15936.412 us; speedup 1.0000x reference)
//
#include <hip/hip_runtime.h>
#include <cmath>

#define BB 64
#define TT 100
#define DD 1024
#define HH 1024
#define H3 3072
#define NOUT 28

__device__ __forceinline__ float sigmoidf_(float x){ return 1.0f/(1.0f + expf(-x)); }

// ---------------- init: zero hd buffer 0 and idx ----------------
__global__ void k_init(float* hd0, int* idx){
    int gid = blockIdx.x*256 + threadIdx.x;
    if (gid < BB*HH) hd0[gid] = 0.0f;
    if (gid < BB) idx[gid] = 0;
}

// ---------------- transpose U [1024][3072] -> Ut [3072][1024] ----------------
__global__ __launch_bounds__(256) void k_transpose(const float* __restrict__ U0,
                                                   const float* __restrict__ U1,
                                                   float* __restrict__ T0,
                                                   float* __restrict__ T1){
    const float* U = blockIdx.z ? U1 : U0;
    float*       T = blockIdx.z ? T1 : T0;
    __shared__ float tile[32][33];
    int tx = threadIdx.x & 31, ty = threadIdx.x >> 5;
    int j0 = blockIdx.x*32, k0 = blockIdx.y*32;
    #pragma unroll
    for (int q=0;q<4;q++){
        int kr = ty + q*8;
        tile[kr][tx] = U[(size_t)(k0+kr)*H3 + j0 + tx];
    }
    __syncthreads();
    #pragma unroll
    for (int q=0;q<4;q++){
        int jr = ty + q*8;
        T[(size_t)(j0+jr)*DD + k0 + tx] = tile[tx][jr];
    }
}

// ---------------- Edec[28][3072] = emb[28][1024] @ decW[1024][3072] + decb[0] ----------------
__global__ __launch_bounds__(256) void k_edec(const float* __restrict__ emb,
                                              const float* __restrict__ W,
                                              const float* __restrict__ b0,
                                              float* __restrict__ E){
    int gid = blockIdx.x*256 + threadIdx.x;   // 28*3072 = 86016 exactly
    int v = gid / H3, j = gid - v*H3;
    float acc = b0[j];
    const float* er = emb + (size_t)v*DD;
    #pragma unroll 4
    for (int k=0;k<DD;k++) acc = fmaf(er[k], W[(size_t)k*H3 + j], acc);
    E[gid] = acc;
}

// ---------------- MX[6400][3072] = x2d[6400][1024] @ encW[1024][3072] + encb[0] ----------------
__global__ __launch_bounds__(256) void k_mxgemm(const float* __restrict__ A,
                                                const float* __restrict__ W,
                                                const float* __restrict__ b0,
                                                float* __restrict__ C){
    __shared__ float aT[32*68];
    __shared__ float bL[32*68];
    int tid = threadIdx.x;
    int row0 = blockIdx.y*64, col0 = blockIdx.x*64;
    int arow = tid>>2, acs = (tid&3)*4;
    int bk   = tid>>3, bcs = (tid&7)*4;
    int ty = tid>>4, tx = tid&15;
    float acc[4][4] = {};
    for (int kk=0; kk<DD; kk+=32){
        #pragma unroll
        for (int i=0;i<2;i++){
            int c = acs + i*16;
            float4 v = *(const float4*)(A + (size_t)(row0+arow)*DD + kk + c);
            aT[(c+0)*68 + arow] = v.x; aT[(c+1)*68 + arow] = v.y;
            aT[(c+2)*68 + arow] = v.z; aT[(c+3)*68 + arow] = v.w;
        }
        #pragma unroll
        for (int i=0;i<2;i++){
            int c = bcs + i*32;
            float4 v = *(const float4*)(W + (size_t)(kk+bk)*H3 + col0 + c);
            *(float4*)(bL + bk*68 + c) = v;
        }
        __syncthreads();
        #pragma unroll
        for (int k=0;k<32;k++){
            float4 a4 = *(const float4*)(aT + k*68 + ty*4);
            float4 b4 = *(const float4*)(bL + k*68 + tx*4);
            acc[0][0]=fmaf(a4.x,b4.x,acc[0][0]); acc[0][1]=fmaf(a4.x,b4.y,acc[0][1]);
            acc[0][2]=fmaf(a4.x,b4.z,acc[0][2]); acc[0][3]=fmaf(a4.x,b4.w,acc[0][3]);
            acc[1][0]=fmaf(a4.y,b4.x,acc[1][0]); acc[1][1]=fmaf(a4.y,b4.y,acc[1][1]);
            acc[1][2]=fmaf(a4.y,b4.z,acc[1][2]); acc[1][3]=fmaf(a4.y,b4.w,acc[1][3]);
            acc[2][0]=fmaf(a4.z,b4.x,acc[2][0]); acc[2][1]=fmaf(a4.z,b4.y,acc[2][1]);
            acc[2][2]=fmaf(a4.z,b4.z,acc[2][2]); acc[2][3]=fmaf(a4.z,b4.w,acc[2][3]);
            acc[3][0]=fmaf(a4.w,b4.x,acc[3][0]); acc[3][1]=fmaf(a4.w,b4.y,acc[3][1]);
            acc[3][2]=fmaf(a4.w,b4.z,acc[3][2]); acc[3][3]=fmaf(a4.w,b4.w,acc[3][3]);
        }
        __syncthreads();
    }
    float4 bb = *(const float4*)(b0 + col0 + tx*4);
    #pragma unroll
    for (int i=0;i<4;i++){
        float4 o;
        o.x = acc[i][0] + bb.x; o.y = acc[i][1] + bb.y;
        o.z = acc[i][2] + bb.z; o.w = acc[i][3] + bb.w;
        *(float4*)(C + (size_t)(row0+ty*4+i)*H3 + col0 + tx*4) = o;
    }
}

// ---------------- fused GRU step: mi = h@Ut + b1 ; gates ; h_out ----------------
// ISDEC=0: mx row = mx + r*mxstr   ISDEC=1: mx row = mx + idx[r]*3072
template<int ISDEC>
__global__ __launch_bounds__(256) void k_gru(const float* __restrict__ hprev, long hstr,
                                             const float* __restrict__ Ut,
                                             const float* __restrict__ b1,
                                             const float* __restrict__ mx, long mxstr,
                                             const int* __restrict__ idxp,
                                             float* __restrict__ hout, long ostr){
    __shared__ float hT[64*66];
    int tid = threadIdx.x;
    int r = tid & 63;
    int j = (blockIdx.x<<2) + (tid>>6);
    int js = __builtin_amdgcn_readfirstlane(j);
    const float* Uz = Ut + (size_t)js*DD;
    const float* Ur = Ut + (size_t)(js+HH)*DD;
    const float* Uh = Ut + (size_t)(js+2*HH)*DD;
    float az=0.f, ar=0.f, ah=0.f;
    if (hprev){
        int srow = tid>>2; int sc = (tid&3)*4;
        for (int kk=0; kk<DD; kk+=64){
            #pragma unroll
            for (int i=0;i<4;i++){
                int c = sc + i*16;
                float4 v = *(const float4*)(hprev + (size_t)srow*hstr + kk + c);
                hT[(c+0)*66 + srow] = v.x; hT[(c+1)*66 + srow] = v.y;
                hT[(c+2)*66 + srow] = v.z; hT[(c+3)*66 + srow] = v.w;
            }
            __syncthreads();
            #pragma unroll
            for (int k4=0;k4<16;k4++){
                float4 uz = *(const float4*)(Uz + kk + k4*4);
                float4 ur = *(const float4*)(Ur + kk + k4*4);
                float4 uh = *(const float4*)(Uh + kk + k4*4);
                float h0 = hT[(k4*4+0)*66 + r];
                float h1 = hT[(k4*4+1)*66 + r];
                float h2 = hT[(k4*4+2)*66 + r];
                float h3 = hT[(k4*4+3)*66 + r];
                az=fmaf(h0,uz.x,az); ar=fmaf(h0,ur.x,ar); ah=fmaf(h0,uh.x,ah);
                az=fmaf(h1,uz.y,az); ar=fmaf(h1,ur.y,ar); ah=fmaf(h1,uh.y,ah);
                az=fmaf(h2,uz.z,az); ar=fmaf(h2,ur.z,ar); ah=fmaf(h2,uh.z,ah);
                az=fmaf(h3,uz.w,az); ar=fmaf(h3,ur.w,ar); ah=fmaf(h3,uh.w,ah);
            }
            __syncthreads();
        }
    }
    const float* mrow = ISDEC ? (mx + (size_t)idxp[r]*H3) : (mx + (size_t)r*mxstr);
    float xz = mrow[js], xr = mrow[js+HH], xh = mrow[js+2*HH];
    float rz = az + b1[js], rr = ar + b1[js+HH], rh = ah + b1[js+2*HH];
    float hp = hprev ? hprev[(size_t)r*hstr + js] : 0.f;
    float zg = sigmoidf_(xz + rz);
    float rg = sigmoidf_(xr + rr);
    float hh = tanhf(xh + rg*rh);
    hout[(size_t)r*ostr + js] = zg*hp + (1.f - zg)*hh;
}

// ---------------- fused: p(t-1)=fc(hd,ctx) -> out + argmax -> idx ; attention -> ctx(t) ----------------
__global__ __launch_bounds__(256) void k_attnfc(int t, const float* __restrict__ hd,
                                                const float* __restrict__ hpe,
                                                const float* __restrict__ scale,
                                                float* __restrict__ ctx,
                                                const float* __restrict__ fcW,
                                                const float* __restrict__ fcb,
                                                float* __restrict__ out,
                                                int* __restrict__ idxo,
                                                int do_p, int do_attn){
    __shared__ float hd_l[1024];
    __shared__ float sc_l[1024];
    __shared__ float s_l[100];
    __shared__ float red[256];
    __shared__ float Sv[4];
    int tid = threadIdx.x, b = blockIdx.x;
    {
        float4 v = *(const float4*)(hd + (size_t)b*HH + tid*4);
        *(float4*)(hd_l + tid*4) = v;
        float4 s = *(const float4*)(scale + tid*4);
        *(float4*)(sc_l + tid*4) = s;
    }
    __syncthreads();
    if (do_p){
        int o = tid % 28, g = tid / 28;
        if (g < 8){
            int d0 = g*128;
            float part = 0.f;
            for (int dd=0; dd<128; dd++){
                int d = d0+dd;
                part = fmaf(hd_l[d],               fcW[d*28 + o],        part);
                part = fmaf(ctx[(size_t)b*HH + d], fcW[(1024+d)*28 + o], part);
            }
            red[g*28 + o] = part;
        }
        __syncthreads();
        if (tid < 28){
            float p = fcb[tid];
            #pragma unroll
            for (int g2=0; g2<8; g2++) p += red[g2*28 + tid];
            out[((size_t)b*TT + (t-1))*NOUT + tid] = p;
            red[tid] = p;
        }
        __syncthreads();
        if (tid == 0){
            float best = red[0]; int bi = 0;
            for (int o2=1;o2<28;o2++){ if (red[o2] > best){ best = red[o2]; bi = o2; } }
            idxo[b] = bi;
        }
        __syncthreads();
    }
    if (do_attn){
        int w = tid>>6, lane = tid&63;
        for (int i=0;i<25;i++){
            int jq = w*25 + i;
            const float* hp = hpe + ((size_t)b*TT + jq)*HH;
            float part = 0.f;
            #pragma unroll
            for (int seg=0; seg<4; seg++){
                int d = seg*256 + lane*4;
                float4 v  = *(const float4*)(hp + d);
                float4 h4 = *(const float4*)(hd_l + d);
                float4 s4 = *(const float4*)(sc_l + d);
                part = fmaf(s4.x, tanhf(h4.x + v.x), part);
                part = fmaf(s4.y, tanhf(h4.y + v.y), part);
                part = fmaf(s4.z, tanhf(h4.z + v.z), part);
                part = fmaf(s4.w, tanhf(h4.w + v.w), part);
            }
            #pragma unroll
            for (int off=32; off; off>>=1) part += __shfl_xor(part, off);
            if (lane == 0) s_l[jq] = part;
        }
        __syncthreads();
        float sv = -3.0e38f;
        if (tid < 100) sv = s_l[tid];
        if (tid < 128){
            float m = sv;
            #pragma unroll
            for (int off=32; off; off>>=1) m = fmaxf(m, __shfl_xor(m, off));
            if ((tid&63)==0) Sv[tid>>6] = m;
        }
        __syncthreads();
        float M = fmaxf(Sv[0], Sv[1]);
        float e = 0.f;
        if (tid < 100){ e = expf(sv - M); s_l[tid] = e; }
        if (tid < 128){
            float se = e;
            #pragma unroll
            for (int off=32; off; off>>=1) se += __shfl_xor(se, off);
            if ((tid&63)==0) Sv[2 + (tid>>6)] = se;
        }
        __syncthreads();
        float rS = 1.0f / (Sv[2] + Sv[3]);
        float4 acc = {0.f,0.f,0.f,0.f};
        int d = tid*4;
        for (int jq=0; jq<100; jq++){
            float wgt = s_l[jq];
            float4 v = *(const float4*)(hpe + ((size_t)b*TT + jq)*HH + d);
            acc.x = fmaf(wgt, v.x, acc.x);
            acc.y = fmaf(wgt, v.y, acc.y);
            acc.z = fmaf(wgt, v.z, acc.z);
            acc.w = fmaf(wgt, v.w, acc.w);
        }
        acc.x *= rS; acc.y *= rS; acc.z *= rS; acc.w *= rS;
        *(float4*)(ctx + (size_t)b*HH + d) = acc;
    }
}

extern "C" void kernel_launch(void* const* d_in, const int* in_sizes, int n_in,
                              void* d_out, int out_size, void* d_ws, size_t ws_size,
                              hipStream_t stream){
    const float* x     = (const float*)d_in[0];
    const float* encW  = (const float*)d_in[1];
    const float* encU  = (const float*)d_in[2];
    const float* encb  = (const float*)d_in[3];
    const float* scale = (const float*)d_in[4];
    const float* emb   = (const float*)d_in[5];
    const float* decW  = (const float*)d_in[6];
    const float* decU  = (const float*)d_in[7];
    const float* decb  = (const float*)d_in[8];
    const float* fcW   = (const float*)d_in[9];
    const float* fcb   = (const float*)d_in[10];
    float* out = (float*)d_out;
    float* ws  = (float*)d_ws;

    float* MX    = ws;                       // 6400*3072      = 19,660,800
    float* encUt = MX    + 19660800;         // 3072*1024
    float* decUt = encUt + 3145728;          // 3072*1024
    float* hpe   = decUt + 3145728;          // 64*100*1024
    float* Edec  = hpe   + 6553600;          // 28*3072
    float* ctx   = Edec  + 86016;            // 64*1024
    float* hdb   = ctx   + 65536;            // 2*64*1024
    int*   idx   = (int*)(hdb + 131072);     // 64

    k_init<<<256,256,0,stream>>>(hdb, idx);
    k_transpose<<<dim3(96,32,2),256,0,stream>>>(encU, decU, encUt, decUt);
    k_edec<<<336,256,0,stream>>>(emb, decW, decb, Edec);
    k_mxgemm<<<dim3(48,100),256,0,stream>>>(x, encW, encb, MX);

    const float* encb1 = encb + H3;
    const float* decb1 = decb + H3;

    // encoder: 100 sequential fused GRU steps
    for (int t=0;t<TT;t++){
        const float* hprev = t ? (hpe + (size_t)(t-1)*HH) : nullptr;
        k_gru<0><<<256,256,0,stream>>>(hprev, (long)TT*HH, encUt, encb1,
                                       MX + (size_t)t*H3, (long)TT*H3, nullptr,
                                       hpe + (size_t)t*HH, (long)TT*HH);
    }
    // decoder: 100 steps of (p/argmax + attention) then GRU
    for (int t=0;t<TT;t++){
        float* hd_cur = hdb + (size_t)(t&1)*65536;
        float* hd_nxt = hdb + (size_t)((t+1)&1)*65536;
        k_attnfc<<<64,256,0,stream>>>(t, hd_cur, hpe, scale, ctx, fcW, fcb, out, idx, t>0, 1);
        k_gru<1><<<256,256,0,stream>>>(hd_cur, (long)HH, decUt, decb1,
                                       Edec, 0L, idx, hd_nxt, (long)HH);
    }
    // final p(99)
    k_attnfc<<<64,256,0,stream>>>(TT, hdb, hpe, scale, ctx, fcW, fcb, out, idx, 1, 0);
}

// Round 2
// 12793.283 us; speedup vs baseline: 1.2457x; 1.2457x over previous
//
#include <hip/hip_runtime.h>

#define TT 100
#define DD 1024
#define HH 1024
#define H3 3072
#define NOUT 28

__device__ __forceinline__ float frcp_(float x){ return __builtin_amdgcn_rcpf(x); }
__device__ __forceinline__ float fsig_(float x){ return frcp_(1.0f + __expf(-x)); }
__device__ __forceinline__ float ftanh_(float x){ return 1.0f - 2.0f*frcp_(__expf(2.0f*x) + 1.0f); }

// ---- grid barrier: per-step monotonic slot, release on arrive, acquire on depart ----
__device__ __forceinline__ void gridbar(int* slot, int target){
    __syncthreads();
    if (threadIdx.x == 0){
        __hip_atomic_fetch_add(slot, 1, __ATOMIC_RELEASE, __HIP_MEMORY_SCOPE_AGENT);
        while (__hip_atomic_load(slot, __ATOMIC_RELAXED, __HIP_MEMORY_SCOPE_AGENT) < target)
            __builtin_amdgcn_s_sleep(2);
        (void)__hip_atomic_load(slot, __ATOMIC_ACQUIRE, __HIP_MEMORY_SCOPE_AGENT);
    }
    __syncthreads();
}

// ---------------- init: zero hd_lin_A + control ints ----------------
__global__ void k_init(float* hla, int* ib){
    int g = blockIdx.x*256 + threadIdx.x;
    if (g < 65536) hla[g] = 0.0f;
    if (g < 448) ib[g] = 0;
}

// ---------------- transpose U [1024][3072] -> Ut [3072][1024] ----------------
__global__ __launch_bounds__(256) void k_transpose(const float* __restrict__ U0,
                                                   const float* __restrict__ U1,
                                                   float* __restrict__ T0,
                                                   float* __restrict__ T1){
    const float* U = blockIdx.z ? U1 : U0;
    float*       T = blockIdx.z ? T1 : T0;
    __shared__ float tile[32][33];
    int tx = threadIdx.x & 31, ty = threadIdx.x >> 5;
    int j0 = blockIdx.x*32, k0 = blockIdx.y*32;
    #pragma unroll
    for (int q=0;q<4;q++){
        int kr = ty + q*8;
        tile[kr][tx] = U[(size_t)(k0+kr)*H3 + j0 + tx];
    }
    __syncthreads();
    #pragma unroll
    for (int q=0;q<4;q++){
        int jr = ty + q*8;
        T[(size_t)(j0+jr)*DD + k0 + tx] = tile[tx][jr];
    }
}

// ---------------- Edec[28][3072] = emb @ decW + decb[0] ----------------
__global__ __launch_bounds__(256) void k_edec(const float* __restrict__ emb,
                                              const float* __restrict__ W,
                                              const float* __restrict__ b0,
                                              float* __restrict__ E){
    int gid = blockIdx.x*256 + threadIdx.x;   // 28*3072 = 86016
    int v = gid / H3, j = gid - v*H3;
    float acc = b0[j];
    const float* er = emb + (size_t)v*DD;
    #pragma unroll 4
    for (int k=0;k<DD;k++) acc = fmaf(er[k], W[(size_t)k*H3 + j], acc);
    E[gid] = acc;
}

// ---------------- MXT[t][col][b] = (x2d @ encW + encb[0]) transposed ----------------
__global__ __launch_bounds__(256) void k_mxgemm(const float* __restrict__ A,
                                                const float* __restrict__ W,
                                                const float* __restrict__ b0,
                                                float* __restrict__ MXT){
    __shared__ float aT[32*68];
    __shared__ float bL[32*68];
    int tid = threadIdx.x;
    int row0 = blockIdx.y*64, col0 = blockIdx.x*64;
    int arow = tid>>2, acs = (tid&3)*4;
    int bk   = tid>>3, bcs = (tid&7)*4;
    int ty = tid>>4, tx = tid&15;
    float acc[4][4] = {};
    for (int kk=0; kk<DD; kk+=32){
        #pragma unroll
        for (int i=0;i<2;i++){
            int c = acs + i*16;
            float4 v = *(const float4*)(A + (size_t)(row0+arow)*DD + kk + c);
            aT[(c+0)*68 + arow] = v.x; aT[(c+1)*68 + arow] = v.y;
            aT[(c+2)*68 + arow] = v.z; aT[(c+3)*68 + arow] = v.w;
        }
        #pragma unroll
        for (int i=0;i<2;i++){
            int c = bcs + i*32;
            float4 v = *(const float4*)(W + (size_t)(kk+bk)*H3 + col0 + c);
            *(float4*)(bL + bk*68 + c) = v;
        }
        __syncthreads();
        #pragma unroll
        for (int k=0;k<32;k++){
            float4 a4 = *(const float4*)(aT + k*68 + ty*4);
            float4 b4 = *(const float4*)(bL + k*68 + tx*4);
            acc[0][0]=fmaf(a4.x,b4.x,acc[0][0]); acc[0][1]=fmaf(a4.x,b4.y,acc[0][1]);
            acc[0][2]=fmaf(a4.x,b4.z,acc[0][2]); acc[0][3]=fmaf(a4.x,b4.w,acc[0][3]);
            acc[1][0]=fmaf(a4.y,b4.x,acc[1][0]); acc[1][1]=fmaf(a4.y,b4.y,acc[1][1]);
            acc[1][2]=fmaf(a4.y,b4.z,acc[1][2]); acc[1][3]=fmaf(a4.y,b4.w,acc[1][3]);
            acc[2][0]=fmaf(a4.z,b4.x,acc[2][0]); acc[2][1]=fmaf(a4.z,b4.y,acc[2][1]);
            acc[2][2]=fmaf(a4.z,b4.z,acc[2][2]); acc[2][3]=fmaf(a4.z,b4.w,acc[2][3]);
            acc[3][0]=fmaf(a4.w,b4.x,acc[3][0]); acc[3][1]=fmaf(a4.w,b4.y,acc[3][1]);
            acc[3][2]=fmaf(a4.w,b4.z,acc[3][2]); acc[3][3]=fmaf(a4.w,b4.w,acc[3][3]);
        }
        __syncthreads();
    }
    float4 bb = *(const float4*)(b0 + col0 + tx*4);
    #pragma unroll
    for (int i=0;i<4;i++){
        int r = row0 + ty*4 + i;
        int bq = r / 100; int tq = r - bq*100;
        float v0 = acc[i][0] + bb.x, v1 = acc[i][1] + bb.y;
        float v2 = acc[i][2] + bb.z, v3 = acc[i][3] + bb.w;
        float* dst = MXT + ((size_t)tq*H3 + col0 + tx*4)*64 + bq;
        dst[0]   = v0; dst[64]  = v1; dst[128] = v2; dst[192] = v3;
    }
}

// ---------------- persistent encoder: 256 WGs x 256 thr, 1 unit per wave ----------------
__global__ __launch_bounds__(256) void k_enc(const float* __restrict__ MXT,
                                             const float* __restrict__ Ut,
                                             const float* __restrict__ b1,
                                             float* __restrict__ hpe,
                                             float* __restrict__ hTa, float* __restrict__ hTb,
                                             int* __restrict__ bar){
    int tid = threadIdx.x;
    int lane = tid & 63;
    int cu = __builtin_amdgcn_readfirstlane((int)blockIdx.x*4 + (tid>>6)); // unit 0..1023
    const float* Uz = Ut + (size_t)cu*DD;
    const float* Ur = Uz + (size_t)HH*DD;
    const float* Uh = Ur + (size_t)HH*DD;
    float bz = b1[cu], br = b1[cu+HH], bh = b1[cu+2*HH];
    for (int t = 0; t < TT; ++t){
        const float* hc = (t&1) ? hTb : hTa;
        float*       hn = (t&1) ? hTa : hTb;
        float az=0.f, ar=0.f, ah=0.f;
        if (t > 0){
            #pragma unroll 8
            for (int k = 0; k < HH; k += 4){
                float4 uz = *(const float4*)(Uz + k);
                float4 ur = *(const float4*)(Ur + k);
                float4 uh = *(const float4*)(Uh + k);
                float h0 = hc[(k+0)*64 + lane];
                float h1 = hc[(k+1)*64 + lane];
                float h2 = hc[(k+2)*64 + lane];
                float h3 = hc[(k+3)*64 + lane];
                az=fmaf(h0,uz.x,az); ar=fmaf(h0,ur.x,ar); ah=fmaf(h0,uh.x,ah);
                az=fmaf(h1,uz.y,az); ar=fmaf(h1,ur.y,ar); ah=fmaf(h1,uh.y,ah);
                az=fmaf(h2,uz.z,az); ar=fmaf(h2,ur.z,ar); ah=fmaf(h2,uh.z,ah);
                az=fmaf(h3,uz.w,az); ar=fmaf(h3,ur.w,ar); ah=fmaf(h3,uh.w,ah);
            }
        }
        const float* mx = MXT + (size_t)t*H3*64;
        float xz = mx[(size_t)cu*64 + lane];
        float xr = mx[(size_t)(cu+HH)*64 + lane];
        float xh = mx[(size_t)(cu+2*HH)*64 + lane];
        float hp = (t>0) ? hc[cu*64 + lane] : 0.f;
        float z  = fsig_(xz + az + bz);
        float r  = fsig_(xr + ar + br);
        float hh = ftanh_(xh + r*(ah + bh));
        float hnew = z*hp + (1.f - z)*hh;
        hn[cu*64 + lane] = hnew;
        hpe[((size_t)lane*TT + t)*HH + cu] = hnew;
        gridbar(bar + t, 256);
    }
}

// ---------------- persistent decoder: 256 WGs x 512 thr ----------------
// waves 0-3: GRU matmul (unit = wg*4 + wave, lane = batch)
// waves 4-7 on wg<64: attention team for b=wg (slice = wave-4); wave4 also does fc+argmax
__global__ __launch_bounds__(512) void k_dec(const float* __restrict__ hpe,
                                             const float* __restrict__ Ut,
                                             const float* __restrict__ b1,
                                             const float* __restrict__ Edec,
                                             const float* __restrict__ scale,
                                             const float* __restrict__ fcW,
                                             const float* __restrict__ fcb,
                                             float* __restrict__ ctxq,
                                             float* __restrict__ hdTa, float* __restrict__ hdTb,
                                             float* __restrict__ hla, float* __restrict__ hlb,
                                             float* __restrict__ out,
                                             int* __restrict__ idx,
                                             int* __restrict__ bar,
                                             int* __restrict__ flagidx){
    __shared__ float s_l[100], s_e[100], m_s[4], S_s[4];
    __shared__ int c_a, c_b, c_fc;
    int tid = threadIdx.x, wg = blockIdx.x;
    if (tid == 0){ c_a = 0; c_b = 0; c_fc = 0; }
    __syncthreads();

    if (tid < 256){
        // ================= matmul role =================
        int lane = tid & 63;
        int cu = __builtin_amdgcn_readfirstlane(wg*4 + (tid>>6));
        const float* Uz = Ut + (size_t)cu*DD;
        const float* Ur = Uz + (size_t)HH*DD;
        const float* Uh = Ur + (size_t)HH*DD;
        float bz = b1[cu], br = b1[cu+HH], bh = b1[cu+2*HH];
        for (int i = 0; i < TT; ++i){
            const float* hc = (i&1) ? hdTb : hdTa;
            float*      hTn = (i&1) ? hdTa : hdTb;
            float*      hln = (i&1) ? hla  : hlb;
            float az=0.f, ar=0.f, ah=0.f;
            if (i > 0){
                #pragma unroll 8
                for (int k = 0; k < HH; k += 4){
                    float4 uz = *(const float4*)(Uz + k);
                    float4 ur = *(const float4*)(Ur + k);
                    float4 uh = *(const float4*)(Uh + k);
                    float h0 = hc[(k+0)*64 + lane];
                    float h1 = hc[(k+1)*64 + lane];
                    float h2 = hc[(k+2)*64 + lane];
                    float h3 = hc[(k+3)*64 + lane];
                    az=fmaf(h0,uz.x,az); ar=fmaf(h0,ur.x,ar); ah=fmaf(h0,uh.x,ah);
                    az=fmaf(h1,uz.y,az); ar=fmaf(h1,ur.y,ar); ah=fmaf(h1,uh.y,ah);
                    az=fmaf(h2,uz.z,az); ar=fmaf(h2,ur.z,ar); ah=fmaf(h2,uh.z,ah);
                    az=fmaf(h3,uz.w,az); ar=fmaf(h3,ur.w,ar); ah=fmaf(h3,uh.w,ah);
                }
            }
            // wait for idx (argmax of p_{i-1}) from the 64 attention teams
            while (__hip_atomic_load(flagidx+i, __ATOMIC_RELAXED, __HIP_MEMORY_SCOPE_AGENT) < 64)
                __builtin_amdgcn_s_sleep(2);
            (void)__hip_atomic_load(flagidx+i, __ATOMIC_ACQUIRE, __HIP_MEMORY_SCOPE_AGENT);
            const float* ed = Edec + (size_t)idx[lane]*H3;
            float xz = ed[cu], xr = ed[cu+HH], xh = ed[cu+2*HH];
            float hp = (i>0) ? hc[cu*64 + lane] : 0.f;
            float z  = fsig_(xz + az + bz);
            float r  = fsig_(xr + ar + br);
            float hh = ftanh_(xh + r*(ah + bh));
            float hnew = z*hp + (1.f - z)*hh;
            hTn[cu*64 + lane] = hnew;
            hln[(size_t)lane*HH + cu] = hnew;
            gridbar(bar + i, 256);
        }
    } else if (wg < 64){
        // ================= attention role, b = wg =================
        int t2 = tid - 256;
        int w = t2 >> 6, lane = t2 & 63, b = wg;
        float sc[16];
        #pragma unroll
        for (int s4=0;s4<4;s4++){
            float4 v = *(const float4*)(scale + lane*16 + s4*4);
            sc[s4*4+0]=v.x; sc[s4*4+1]=v.y; sc[s4*4+2]=v.z; sc[s4*4+3]=v.w;
        }
        int j0 = w*25;
        for (int i = 0; i < TT; ++i){
            const float* hdl = (i&1) ? hlb : hla;
            float q[16];
            #pragma unroll
            for (int s4=0;s4<4;s4++){
                float4 v = *(const float4*)(hdl + (size_t)b*HH + lane*16 + s4*4);
                q[s4*4+0]=v.x; q[s4*4+1]=v.y; q[s4*4+2]=v.z; q[s4*4+3]=v.w;
            }
            if (w == 0){
                if (i > 0){
                    // fc for p_{i-1} = [hd_i, ctx_{i-1}] @ fcW + fcb ; argmax -> idx
                    float acc[NOUT];
                    #pragma unroll
                    for (int o=0;o<NOUT;o++) acc[o] = 0.f;
                    #pragma unroll
                    for (int dd=0; dd<16; ++dd){
                        int d = lane*16 + dd;
                        float hv = q[dd];
                        float cv = ctxq[(size_t)(0*64+b)*HH + d] + ctxq[(size_t)(1*64+b)*HH + d]
                                 + ctxq[(size_t)(2*64+b)*HH + d] + ctxq[(size_t)(3*64+b)*HH + d];
                        const float* w0 = fcW + (size_t)d*NOUT;
                        const float* w1 = fcW + (size_t)(d+HH)*NOUT;
                        #pragma unroll
                        for (int o=0;o<NOUT;o++) acc[o] += hv*w0[o] + cv*w1[o];
                    }
                    #pragma unroll
                    for (int o=0;o<NOUT;o++){
                        #pragma unroll
                        for (int m=1;m<64;m<<=1) acc[o] += __shfl_xor(acc[o], m);
                    }
                    float bv = -3.0e38f; int bi = 0; float vout = 0.f;
                    #pragma unroll
                    for (int o=0;o<NOUT;o++){
                        float p = acc[o] + fcb[o];
                        if (lane == o) vout = p;
                        if (p > bv){ bv = p; bi = o; }
                    }
                    if (lane < NOUT) out[((size_t)b*TT + (i-1))*NOUT + lane] = vout;
                    if (lane == 0) idx[b] = bi;
                }
                if (lane == 0){
                    __hip_atomic_fetch_add(flagidx+i, 1, __ATOMIC_RELEASE, __HIP_MEMORY_SCOPE_AGENT);
                    atomicAdd(&c_fc, 1);
                }
            }
            // S1: scores for this wave's 25 j's
            float mw = -3.0e38f;
            for (int jj=0;jj<25;jj++){
                int j = j0 + jj;
                const float* hp = hpe + ((size_t)b*TT + j)*HH + lane*16;
                float s = 0.f;
                #pragma unroll
                for (int s4=0;s4<4;s4++){
                    float4 v = *(const float4*)(hp + s4*4);
                    s += sc[s4*4+0]*ftanh_(q[s4*4+0] + v.x);
                    s += sc[s4*4+1]*ftanh_(q[s4*4+1] + v.y);
                    s += sc[s4*4+2]*ftanh_(q[s4*4+2] + v.z);
                    s += sc[s4*4+3]*ftanh_(q[s4*4+3] + v.w);
                }
                #pragma unroll
                for (int m=1;m<64;m<<=1) s += __shfl_xor(s, m);
                if (lane == 0) s_l[j] = s;
                mw = fmaxf(mw, s);
            }
            if (lane == 0) m_s[w] = mw;
            __threadfence_block();
            if (lane == 0) atomicAdd(&c_a, 1);
            { volatile int* vc = &c_a; while (*vc < 4*(i+1)) {} }
            __threadfence_block();
            // S2: exp + partial sums
            float M = fmaxf(fmaxf(m_s[0],m_s[1]), fmaxf(m_s[2],m_s[3]));
            float e = 0.f;
            if (lane < 25){ e = __expf(s_l[j0+lane] - M); s_e[j0+lane] = e; }
            float Sw = e;
            #pragma unroll
            for (int m=1;m<64;m<<=1) Sw += __shfl_xor(Sw, m);
            if (lane == 0) S_s[w] = Sw;
            __threadfence_block();
            if (lane == 0) atomicAdd(&c_b, 1);
            { volatile int* vc = &c_b; while (*vc < 4*(i+1)) {} }
            __threadfence_block();
            float S = S_s[0]+S_s[1]+S_s[2]+S_s[3];
            float rinv = frcp_(S);
            // don't overwrite ctxq until wave4's fc (which reads prev ctxq) is done
            { volatile int* vc = &c_fc; while (*vc < (i+1)) {} }
            __threadfence_block();
            // S3: ctx partial for this wave's 25 j's
            float a[16];
            #pragma unroll
            for (int s4=0;s4<16;s4++) a[s4] = 0.f;
            for (int jj=0;jj<25;jj++){
                int j = j0 + jj;
                float wgt = s_e[j];
                const float* hp = hpe + ((size_t)b*TT + j)*HH + lane*16;
                #pragma unroll
                for (int s4=0;s4<4;s4++){
                    float4 v = *(const float4*)(hp + s4*4);
                    a[s4*4+0] = fmaf(wgt, v.x, a[s4*4+0]);
                    a[s4*4+1] = fmaf(wgt, v.y, a[s4*4+1]);
                    a[s4*4+2] = fmaf(wgt, v.z, a[s4*4+2]);
                    a[s4*4+3] = fmaf(wgt, v.w, a[s4*4+3]);
                }
            }
            #pragma unroll
            for (int s4=0;s4<4;s4++){
                float4 o4;
                o4.x = a[s4*4+0]*rinv; o4.y = a[s4*4+1]*rinv;
                o4.z = a[s4*4+2]*rinv; o4.w = a[s4*4+3]*rinv;
                *(float4*)(ctxq + ((size_t)w*64 + b)*HH + lane*16 + s4*4) = o4;
            }
            gridbar(bar + i, 256);
        }
        // epilogue: final fc -> out[b][99], uses hd_100 (in hla: 100 even) + ctx_99
        if (w == 0){
            const float* hdl = hla;
            float q[16];
            #pragma unroll
            for (int s4=0;s4<4;s4++){
                float4 v = *(const float4*)(hdl + (size_t)b*HH + lane*16 + s4*4);
                q[s4*4+0]=v.x; q[s4*4+1]=v.y; q[s4*4+2]=v.z; q[s4*4+3]=v.w;
            }
            float acc[NOUT];
            #pragma unroll
            for (int o=0;o<NOUT;o++) acc[o] = 0.f;
            #pragma unroll
            for (int dd=0; dd<16; ++dd){
                int d = lane*16 + dd;
                float hv = q[dd];
                float cv = ctxq[(size_t)(0*64+b)*HH + d] + ctxq[(size_t)(1*64+b)*HH + d]
                         + ctxq[(size_t)(2*64+b)*HH + d] + ctxq[(size_t)(3*64+b)*HH + d];
                const float* w0 = fcW + (size_t)d*NOUT;
                const float* w1 = fcW + (size_t)(d+HH)*NOUT;
                #pragma unroll
                for (int o=0;o<NOUT;o++) acc[o] += hv*w0[o] + cv*w1[o];
            }
            #pragma unroll
            for (int o=0;o<NOUT;o++){
                #pragma unroll
                for (int m=1;m<64;m<<=1) acc[o] += __shfl_xor(acc[o], m);
            }
            float vout = 0.f;
            #pragma unroll
            for (int o=0;o<NOUT;o++){
                float p = acc[o] + fcb[o];
                if (lane == o) vout = p;
            }
            if (lane < NOUT) out[((size_t)b*TT + 99)*NOUT + lane] = vout;
        }
    } else {
        // idle upper waves of wg>=64: just keep barrier counts aligned
        for (int i = 0; i < TT; ++i) gridbar(bar + i, 256);
    }
}

extern "C" void kernel_launch(void* const* d_in, const int* in_sizes, int n_in,
                              void* d_out, int out_size, void* d_ws, size_t ws_size,
                              hipStream_t stream){
    (void)in_sizes; (void)n_in; (void)out_size; (void)ws_size;
    const float* x     = (const float*)d_in[0];
    const float* encW  = (const float*)d_in[1];
    const float* encU  = (const float*)d_in[2];
    const float* encb  = (const float*)d_in[3];
    const float* scale = (const float*)d_in[4];
    const float* emb   = (const float*)d_in[5];
    const float* decW  = (const float*)d_in[6];
    const float* decU  = (const float*)d_in[7];
    const float* decb  = (const float*)d_in[8];
    const float* fcW   = (const float*)d_in[9];
    const float* fcb   = (const float*)d_in[10];
    float* out = (float*)d_out;
    float* ws  = (float*)d_ws;

    float* MXT   = ws;                        // 100*3072*64 = 19,660,800
    float* encUt = MXT   + 19660800;          // 3,145,728
    float* decUt = encUt + 3145728;           // 3,145,728
    float* hpe   = decUt + 3145728;           // 6,553,600
    float* Edec  = hpe   + 6553600;           // 86,016
    float* ctxq  = Edec  + 86016;             // 4*64*1024 = 262,144
    float* hTa   = ctxq  + 262144;            // 65,536
    float* hTb   = hTa   + 65536;             // 65,536
    float* hdTa  = hTb   + 65536;             // 65,536
    float* hdTb  = hdTa  + 65536;             // 65,536
    float* hla   = hdTb  + 65536;             // 65,536
    float* hlb   = hla   + 65536;             // 65,536
    int*   ib    = (int*)(hlb + 65536);       // idx[64] bar_enc[128] bar_dec[128] flagidx[128]
    int*   idx     = ib;
    int*   bar_enc = ib + 64;
    int*   bar_dec = ib + 64 + 128;
    int*   flagidx = ib + 64 + 256;

    const float* encb1 = encb + H3;
    const float* decb1 = decb + H3;

    k_init<<<256,256,0,stream>>>(hla, ib);
    k_transpose<<<dim3(96,32,2),256,0,stream>>>(encU, decU, encUt, decUt);
    k_edec<<<336,256,0,stream>>>(emb, decW, decb, Edec);
    k_mxgemm<<<dim3(48,100),256,0,stream>>>(x, encW, encb, MXT);
    k_enc<<<256,256,0,stream>>>(MXT, encUt, encb1, hpe, hTa, hTb, bar_enc);
    k_dec<<<256,512,0,stream>>>(hpe, decUt, decb1, Edec, scale, fcW, fcb,
                                ctxq, hdTa, hdTb, hla, hlb, out, idx, bar_dec, flagidx);
}

// Round 4
// 11062.755 us; speedup vs baseline: 1.4405x; 1.1564x over previous
//
#include <hip/hip_runtime.h>

#define TT 100
#define HH 1024
#define H3 3072
#define NOUT 28

#define AGENT __HIP_MEMORY_SCOPE_AGENT
#define WGRP  __HIP_MEMORY_SCOPE_WORKGROUP
#define SPIN_CAP (1u<<27)

__device__ __forceinline__ float frcp_(float x){ return __builtin_amdgcn_rcpf(x); }
__device__ __forceinline__ float fsig_(float x){ return frcp_(1.0f + __expf(-x)); }
__device__ __forceinline__ float ftanh_(float x){ return 1.0f - 2.0f*frcp_(__expf(2.0f*x) + 1.0f); }

__device__ __forceinline__ unsigned long long aload8(const unsigned long long* p){
    return __hip_atomic_load(p, __ATOMIC_RELAXED, AGENT);
}
__device__ __forceinline__ unsigned aload4(const int* p){
    return (unsigned)__hip_atomic_load(p, __ATOMIC_RELAXED, AGENT);
}

// grid barrier: 16 padded sub-counters per slot (slot stride = 256 ints), relaxed only.
// Data crossing WGs travels via device-scope atomics (coherence point), so no fences needed.
__device__ __forceinline__ void gridbar(int* slot, int sub, int target){
    __syncthreads();   // drains vmcnt -> device-scope stores complete before arrival
    if (threadIdx.x == 0){
        __hip_atomic_fetch_add(slot + sub*16, 1, __ATOMIC_RELAXED, AGENT);
        unsigned gy = 0; int s;
        do {
            s = 0;
            #pragma unroll
            for (int c=0;c<16;c++) s += __hip_atomic_load(slot + c*16, __ATOMIC_RELAXED, AGENT);
            if (s < target){ if (++gy > SPIN_CAP) break; __builtin_amdgcn_s_sleep(1); }
        } while (s < target);
    }
    __syncthreads();
}

// barrier among the 4 matmul waves only (LDS counter, monotonic target), capped
__device__ __forceinline__ void wbar4(int* c, int tgt){
    asm volatile("s_waitcnt lgkmcnt(0)" ::: "memory");
    if ((threadIdx.x & 63) == 0) __hip_atomic_fetch_add(c, 1, __ATOMIC_RELAXED, WGRP);
    unsigned gy = 0;
    while (__hip_atomic_load(c, __ATOMIC_RELAXED, WGRP) < tgt){ if (++gy > SPIN_CAP) break; }
    asm volatile("" ::: "memory");
}

// ---------------- init: zero control ints ----------------
__global__ void k_init(int* ib, int n){
    int g = blockIdx.x*256 + threadIdx.x;
    if (g < n) ib[g] = 0;
}

// ---------------- transpose U [1024][3072] -> Ut [3072][1024] ----------------
__global__ __launch_bounds__(256) void k_transpose(const float* __restrict__ U0,
                                                   const float* __restrict__ U1,
                                                   float* __restrict__ T0,
                                                   float* __restrict__ T1){
    const float* U = blockIdx.z ? U1 : U0;
    float*       T = blockIdx.z ? T1 : T0;
    __shared__ float tile[32][33];
    int tx = threadIdx.x & 31, ty = threadIdx.x >> 5;
    int j0 = blockIdx.x*32, k0 = blockIdx.y*32;
    #pragma unroll
    for (int q=0;q<4;q++){
        int kr = ty + q*8;
        tile[kr][tx] = U[(size_t)(k0+kr)*H3 + j0 + tx];
    }
    __syncthreads();
    #pragma unroll
    for (int q=0;q<4;q++){
        int jr = ty + q*8;
        T[(size_t)(j0+jr)*HH + k0 + tx] = tile[tx][jr];
    }
}

// ---------------- Edec[28][3072] = emb @ decW + decb[0] ----------------
__global__ __launch_bounds__(256) void k_edec(const float* __restrict__ emb,
                                              const float* __restrict__ W,
                                              const float* __restrict__ b0,
                                              float* __restrict__ E){
    int gid = blockIdx.x*256 + threadIdx.x;   // 28*3072 = 86016
    int v = gid / H3, j = gid - v*H3;
    float acc = b0[j];
    const float* er = emb + (size_t)v*HH;
    #pragma unroll 4
    for (int k=0;k<HH;k++) acc = fmaf(er[k], W[(size_t)k*H3 + j], acc);
    E[gid] = acc;
}

// ---------------- MXT[t][col][b] = (x2d @ encW + encb[0]) transposed ----------------
__global__ __launch_bounds__(256) void k_mxgemm(const float* __restrict__ A,
                                                const float* __restrict__ W,
                                                const float* __restrict__ b0,
                                                float* __restrict__ MXT){
    __shared__ float aT[32*68];
    __shared__ float bL[32*68];
    int tid = threadIdx.x;
    int row0 = blockIdx.y*64, col0 = blockIdx.x*64;
    int arow = tid>>2, acs = (tid&3)*4;
    int bk   = tid>>3, bcs = (tid&7)*4;
    int ty = tid>>4, tx = tid&15;
    float acc[4][4] = {};
    for (int kk=0; kk<HH; kk+=32){
        #pragma unroll
        for (int i=0;i<2;i++){
            int c = acs + i*16;
            float4 v = *(const float4*)(A + (size_t)(row0+arow)*HH + kk + c);
            aT[(c+0)*68 + arow] = v.x; aT[(c+1)*68 + arow] = v.y;
            aT[(c+2)*68 + arow] = v.z; aT[(c+3)*68 + arow] = v.w;
        }
        #pragma unroll
        for (int i=0;i<2;i++){
            int c = bcs + i*32;
            float4 v = *(const float4*)(W + (size_t)(kk+bk)*H3 + col0 + c);
            *(float4*)(bL + bk*68 + c) = v;
        }
        __syncthreads();
        #pragma unroll
        for (int k=0;k<32;k++){
            float4 a4 = *(const float4*)(aT + k*68 + ty*4);
            float4 b4 = *(const float4*)(bL + k*68 + tx*4);
            acc[0][0]=fmaf(a4.x,b4.x,acc[0][0]); acc[0][1]=fmaf(a4.x,b4.y,acc[0][1]);
            acc[0][2]=fmaf(a4.x,b4.z,acc[0][2]); acc[0][3]=fmaf(a4.x,b4.w,acc[0][3]);
            acc[1][0]=fmaf(a4.y,b4.x,acc[1][0]); acc[1][1]=fmaf(a4.y,b4.y,acc[1][1]);
            acc[1][2]=fmaf(a4.y,b4.z,acc[1][2]); acc[1][3]=fmaf(a4.y,b4.w,acc[1][3]);
            acc[2][0]=fmaf(a4.z,b4.x,acc[2][0]); acc[2][1]=fmaf(a4.z,b4.y,acc[2][1]);
            acc[2][2]=fmaf(a4.z,b4.z,acc[2][2]); acc[2][3]=fmaf(a4.z,b4.w,acc[2][3]);
            acc[3][0]=fmaf(a4.w,b4.x,acc[3][0]); acc[3][1]=fmaf(a4.w,b4.y,acc[3][1]);
            acc[3][2]=fmaf(a4.w,b4.z,acc[3][2]); acc[3][3]=fmaf(a4.w,b4.w,acc[3][3]);
        }
        __syncthreads();
    }
    float4 bb = *(const float4*)(b0 + col0 + tx*4);
    #pragma unroll
    for (int i=0;i<4;i++){
        int r = row0 + ty*4 + i;
        int bq = r / 100; int tq = r - bq*100;
        float v0 = acc[i][0] + bb.x, v1 = acc[i][1] + bb.y;
        float v2 = acc[i][2] + bb.z, v3 = acc[i][3] + bb.w;
        float* dst = MXT + ((size_t)tq*H3 + col0 + tx*4)*64 + bq;
        dst[0]   = v0; dst[64]  = v1; dst[128] = v2; dst[192] = v3;
    }
}

// ---------------- persistent encoder: 256 WGs x 256 thr ----------------
// hT = ping-pong [2][1024][64]; staged to LDS via device-scope 8B atomic loads
__global__ __launch_bounds__(256) void k_enc(const float* __restrict__ MXT,
                                             const float* __restrict__ Ut,
                                             const float* __restrict__ b1,
                                             float* __restrict__ hpe,
                                             float* __restrict__ hT,
                                             int* __restrict__ bar){
    __shared__ float hs[2][16384];
    int tid = threadIdx.x, lane = tid & 63;
    int wg = blockIdx.x;
    int sub = wg & 15;
    int cu = __builtin_amdgcn_readfirstlane(wg*4 + (tid>>6));
    const float* Uz = Ut + (size_t)cu*HH;
    const float* Ur = Uz + (size_t)HH*HH;
    const float* Uh = Ur + (size_t)HH*HH;
    float bz = b1[cu], br = b1[cu+HH], bh = b1[cu+2*HH];
    for (int t=0; t<TT; ++t){
        int cur = t & 1;
        const float* mx = MXT + (size_t)t*H3*64;
        float xz = mx[(size_t)cu*64 + lane];
        float xr = mx[(size_t)(cu+HH)*64 + lane];
        float xh = mx[(size_t)(cu+2*HH)*64 + lane];
        float az=0.f, ar=0.f, ah=0.f, hp=0.f;
        if (t > 0){
            const unsigned long long* g8 = (const unsigned long long*)(hT + (size_t)cur*65536);
            unsigned long long sv[32];
            #pragma unroll
            for (int s=0;s<32;s++) sv[s] = aload8(g8 + s*256 + tid);
            #pragma unroll
            for (int s=0;s<32;s++) ((unsigned long long*)hs[0])[s*256 + tid] = sv[s];
            __syncthreads();
            for (int q=0;q<4;++q){
                if (q<3){
                    #pragma unroll
                    for (int s=0;s<32;s++) sv[s] = aload8(g8 + (q+1)*8192 + s*256 + tid);
                }
                const float* hb = hs[q&1];
                const float* Uzq = Uz + q*256;
                const float* Urq = Ur + q*256;
                const float* Uhq = Uh + q*256;
                #pragma unroll 8
                for (int k=0;k<256;++k){
                    float h = hb[k*64 + lane];
                    az = fmaf(h, Uzq[k], az);
                    ar = fmaf(h, Urq[k], ar);
                    ah = fmaf(h, Uhq[k], ah);
                }
                if ((cu>>8) == q) hp = hb[(cu&255)*64 + lane];
                if (q<3){
                    #pragma unroll
                    for (int s=0;s<32;s++) ((unsigned long long*)hs[(q+1)&1])[s*256 + tid] = sv[s];
                }
                __syncthreads();
            }
        }
        float z  = fsig_(xz + az + bz);
        float r  = fsig_(xr + ar + br);
        float hh = ftanh_(xh + r*(ah + bh));
        float hnew = z*hp + (1.f - z)*hh;
        __hip_atomic_store(hT + (size_t)(cur^1)*65536 + cu*64 + lane, hnew, __ATOMIC_RELAXED, AGENT);
        hpe[((size_t)lane*TT + t)*HH + cu] = hnew;
        gridbar(bar + (size_t)t*256, sub, 256);
    }
}

// ---------------- persistent decoder: 256 WGs x 512 thr ----------------
// waves 0-3: GRU matmul (unit = wg*4+wave, lane = batch); waves 4-7 on wg<64: attention team b=wg
__global__ __launch_bounds__(512) void k_dec(const float* __restrict__ hpe,
                                             const float* __restrict__ Ut,
                                             const float* __restrict__ b1,
                                             const float* __restrict__ Edec,
                                             const float* __restrict__ scale,
                                             const float* __restrict__ fcW,
                                             const float* __restrict__ fcb,
                                             float* __restrict__ hdT,
                                             float* __restrict__ hdl,
                                             float* __restrict__ out,
                                             int* __restrict__ idx_t,
                                             int* __restrict__ bar,
                                             int* __restrict__ flagidx){
    __shared__ float hs[2][16384];
    __shared__ float ctxs[4][1024];
    __shared__ float s_l[128], s_e[128], m_s[4], S_s[4];
    __shared__ int c_a, c_b, c_fc, go, cstg;
    int tid = threadIdx.x, wg = blockIdx.x;
    if (tid == 0){ c_a=0; c_b=0; c_fc=0; go=0; cstg=0; }
    __syncthreads();

    if (tid < 256){
        // ============ matmul role ============
        int lane = tid & 63;
        int sub = wg & 15;
        int cu = __builtin_amdgcn_readfirstlane(wg*4 + (tid>>6));
        const float* Uz = Ut + (size_t)cu*HH;
        const float* Ur = Uz + (size_t)HH*HH;
        const float* Uh = Ur + (size_t)HH*HH;
        float bz = b1[cu], br = b1[cu+HH], bh = b1[cu+2*HH];
        int stgt = 0;
        for (int i=0; i<TT; ++i){
            int cur = i & 1;
            float az=0.f, ar=0.f, ah=0.f, hp=0.f;
            if (i > 0){
                const unsigned long long* g8 = (const unsigned long long*)(hdT + (size_t)cur*65536);
                unsigned long long sv[32];
                #pragma unroll
                for (int s=0;s<32;s++) sv[s] = aload8(g8 + s*256 + tid);
                #pragma unroll
                for (int s=0;s<32;s++) ((unsigned long long*)hs[0])[s*256 + tid] = sv[s];
                wbar4(&cstg, stgt += 4);
                for (int q=0;q<4;++q){
                    if (q<3){
                        #pragma unroll
                        for (int s=0;s<32;s++) sv[s] = aload8(g8 + (q+1)*8192 + s*256 + tid);
                    }
                    const float* hb = hs[q&1];
                    const float* Uzq = Uz + q*256;
                    const float* Urq = Ur + q*256;
                    const float* Uhq = Uh + q*256;
                    #pragma unroll 8
                    for (int k=0;k<256;++k){
                        float h = hb[k*64 + lane];
                        az = fmaf(h, Uzq[k], az);
                        ar = fmaf(h, Urq[k], ar);
                        ah = fmaf(h, Uhq[k], ah);
                    }
                    if ((cu>>8) == q) hp = hb[(cu&255)*64 + lane];
                    if (q<3){
                        #pragma unroll
                        for (int s=0;s<32;s++) ((unsigned long long*)hs[(q+1)&1])[s*256 + tid] = sv[s];
                    }
                    wbar4(&cstg, stgt += 4);
                }
            }
            // wait for idx(i): single poller + LDS broadcast (capped)
            if (tid == 0){
                unsigned gy = 0; int s;
                do {
                    s = 0;
                    #pragma unroll
                    for (int c=0;c<8;c++) s += __hip_atomic_load(flagidx + (size_t)i*128 + c*16, __ATOMIC_RELAXED, AGENT);
                    if (s < 64){ if (++gy > SPIN_CAP) break; __builtin_amdgcn_s_sleep(1); }
                } while (s < 64);
                __hip_atomic_store(&go, i+1, __ATOMIC_RELAXED, WGRP);
            }
            { unsigned gy=0; while (__hip_atomic_load(&go, __ATOMIC_RELAXED, WGRP) < i+1){ if (++gy > SPIN_CAP) break; } }
            asm volatile("" ::: "memory");
            unsigned mi = aload4(idx_t + (size_t)i*64 + lane);
            if (mi > 27u) mi = 0;
            const float* ed = Edec + (size_t)mi*H3;
            float xz = ed[cu], xr = ed[cu+HH], xh = ed[cu+2*HH];
            float z  = fsig_(xz + az + bz);
            float r  = fsig_(xr + ar + br);
            float hh = ftanh_(xh + r*(ah + bh));
            float hnew = z*hp + (1.f - z)*hh;
            __hip_atomic_store(hdT + (size_t)(cur^1)*65536 + cu*64 + lane, hnew, __ATOMIC_RELAXED, AGENT);
            __hip_atomic_store(hdl + (size_t)(cur^1)*65536 + (size_t)lane*HH + cu, hnew, __ATOMIC_RELAXED, AGENT);
            gridbar(bar + (size_t)i*256, sub, 256);
        }
    } else if (wg < 64){
        // ============ attention team for batch b = wg ============
        int t2 = tid - 256;
        int w = t2 >> 6, lane = t2 & 63, b = wg;
        float sc[16];
        #pragma unroll
        for (int s4=0;s4<4;s4++){
            float4 v = *(const float4*)(scale + lane*16 + s4*4);
            sc[s4*4+0]=v.x; sc[s4*4+1]=v.y; sc[s4*4+2]=v.z; sc[s4*4+3]=v.w;
        }
        int j0 = w*25;
        for (int i=0; i<TT; ++i){
            float q[16];
            if (i == 0){
                #pragma unroll
                for (int d=0;d<16;d++) q[d]=0.f;
            } else {
                const unsigned long long* hq8 = (const unsigned long long*)(hdl + (size_t)(i&1)*65536 + (size_t)b*HH) + lane*8;
                #pragma unroll
                for (int s8=0;s8<8;s8++){
                    unsigned long long v = aload8(hq8 + s8);
                    q[2*s8+0] = __uint_as_float((unsigned)v);
                    q[2*s8+1] = __uint_as_float((unsigned)(v>>32));
                }
            }
            if (w == 0){
                if (i > 0){
                    float acc[NOUT];
                    #pragma unroll
                    for (int o=0;o<NOUT;o++) acc[o]=0.f;
                    float cv[16];
                    #pragma unroll
                    for (int s4=0;s4<4;s4++){
                        float4 c0 = ((const float4*)ctxs[0])[lane*4+s4];
                        float4 c1 = ((const float4*)ctxs[1])[lane*4+s4];
                        float4 c2 = ((const float4*)ctxs[2])[lane*4+s4];
                        float4 c3 = ((const float4*)ctxs[3])[lane*4+s4];
                        cv[s4*4+0]=c0.x+c1.x+c2.x+c3.x;
                        cv[s4*4+1]=c0.y+c1.y+c2.y+c3.y;
                        cv[s4*4+2]=c0.z+c1.z+c2.z+c3.z;
                        cv[s4*4+3]=c0.w+c1.w+c2.w+c3.w;
                    }
                    #pragma unroll
                    for (int dd=0;dd<16;++dd){
                        int d = lane*16 + dd;
                        const float* w0p = fcW + (size_t)d*NOUT;
                        const float* w1p = fcW + (size_t)(d+HH)*NOUT;
                        float hv=q[dd], cvv=cv[dd];
                        #pragma unroll
                        for (int o=0;o<NOUT;o++) acc[o] = fmaf(hv, w0p[o], fmaf(cvv, w1p[o], acc[o]));
                    }
                    #pragma unroll
                    for (int o=0;o<NOUT;o++){
                        #pragma unroll
                        for (int m=1;m<64;m<<=1) acc[o] += __shfl_xor(acc[o], m);
                    }
                    float bv=-3.0e38f; int bi=0;
                    #pragma unroll
                    for (int o=0;o<NOUT;o++){
                        float p = acc[o] + fcb[o];
                        acc[o] = p;
                        if (p > bv){ bv = p; bi = o; }
                    }
                    float vout = 0.f;
                    #pragma unroll
                    for (int o=0;o<NOUT;o++) if (lane == o) vout = acc[o];
                    if (lane < NOUT) out[((size_t)b*TT + (i-1))*NOUT + lane] = vout;
                    if (lane == 0){
                        __hip_atomic_store(idx_t + (size_t)i*64 + b, bi, __ATOMIC_RELAXED, AGENT);
                        asm volatile("s_waitcnt vmcnt(0)" ::: "memory");
                    }
                }
                if (lane == 0){
                    __hip_atomic_fetch_add(flagidx + (size_t)i*128 + (b&7)*16, 1, __ATOMIC_RELAXED, AGENT);
                    __hip_atomic_fetch_add(&c_fc, 1, __ATOMIC_RELAXED, WGRP);
                }
            }
            // S1: scores
            float mw = -3.0e38f;
            for (int jj=0;jj<25;jj++){
                int j = j0 + jj;
                const float* hpj = hpe + ((size_t)b*TT + j)*HH + lane*16;
                float s = 0.f;
                #pragma unroll
                for (int s4=0;s4<4;s4++){
                    float4 v = *(const float4*)(hpj + s4*4);
                    s += sc[s4*4+0]*ftanh_(q[s4*4+0] + v.x);
                    s += sc[s4*4+1]*ftanh_(q[s4*4+1] + v.y);
                    s += sc[s4*4+2]*ftanh_(q[s4*4+2] + v.z);
                    s += sc[s4*4+3]*ftanh_(q[s4*4+3] + v.w);
                }
                #pragma unroll
                for (int m=1;m<64;m<<=1) s += __shfl_xor(s, m);
                if (lane == 0) s_l[j] = s;
                mw = fmaxf(mw, s);
            }
            if (lane == 0) m_s[w] = mw;
            asm volatile("s_waitcnt lgkmcnt(0)" ::: "memory");
            if (lane == 0) __hip_atomic_fetch_add(&c_a, 1, __ATOMIC_RELAXED, WGRP);
            { unsigned gy=0; while (__hip_atomic_load(&c_a, __ATOMIC_RELAXED, WGRP) < 4*(i+1)){ if (++gy > SPIN_CAP) break; } }
            asm volatile("" ::: "memory");
            float M = fmaxf(fmaxf(m_s[0],m_s[1]), fmaxf(m_s[2],m_s[3]));
            float e = 0.f;
            if (lane < 25){ e = __expf(s_l[j0+lane] - M); s_e[j0+lane] = e; }
            float Sw = e;
            #pragma unroll
            for (int m=1;m<64;m<<=1) Sw += __shfl_xor(Sw, m);
            if (lane == 0) S_s[w] = Sw;
            asm volatile("s_waitcnt lgkmcnt(0)" ::: "memory");
            if (lane == 0) __hip_atomic_fetch_add(&c_b, 1, __ATOMIC_RELAXED, WGRP);
            { unsigned gy=0; while (__hip_atomic_load(&c_b, __ATOMIC_RELAXED, WGRP) < 4*(i+1)){ if (++gy > SPIN_CAP) break; } }
            asm volatile("" ::: "memory");
            float rinv = frcp_(S_s[0]+S_s[1]+S_s[2]+S_s[3]);
            // wait until fc consumed ctxs of step i-1
            { unsigned gy=0; while (__hip_atomic_load(&c_fc, __ATOMIC_RELAXED, WGRP) < i+1){ if (++gy > SPIN_CAP) break; } }
            asm volatile("" ::: "memory");
            // S3: ctx partials -> LDS
            float a[16];
            #pragma unroll
            for (int s4=0;s4<16;s4++) a[s4]=0.f;
            for (int jj=0;jj<25;jj++){
                int j = j0 + jj;
                float wgt = s_e[j];
                const float* hpj = hpe + ((size_t)b*TT + j)*HH + lane*16;
                #pragma unroll
                for (int s4=0;s4<4;s4++){
                    float4 v = *(const float4*)(hpj + s4*4);
                    a[s4*4+0] = fmaf(wgt, v.x, a[s4*4+0]);
                    a[s4*4+1] = fmaf(wgt, v.y, a[s4*4+1]);
                    a[s4*4+2] = fmaf(wgt, v.z, a[s4*4+2]);
                    a[s4*4+3] = fmaf(wgt, v.w, a[s4*4+3]);
                }
            }
            #pragma unroll
            for (int s4=0;s4<4;s4++){
                float4 o4;
                o4.x=a[s4*4+0]*rinv; o4.y=a[s4*4+1]*rinv;
                o4.z=a[s4*4+2]*rinv; o4.w=a[s4*4+3]*rinv;
                ((float4*)ctxs[w])[lane*4 + s4] = o4;
            }
            gridbar(bar + (size_t)i*256, wg & 15, 256);
        }
        // epilogue: p(99) = [hd(100), ctx(99)] @ fc ; hd(100) is in hdl[0] (i=99: cur=1, wrote cur^1=0)
        if (w == 0){
            const unsigned long long* hq8 = (const unsigned long long*)(hdl + (size_t)b*HH) + lane*8;
            float q[16];
            #pragma unroll
            for (int s8=0;s8<8;s8++){
                unsigned long long v = aload8(hq8 + s8);
                q[2*s8+0] = __uint_as_float((unsigned)v);
                q[2*s8+1] = __uint_as_float((unsigned)(v>>32));
            }
            float acc[NOUT];
            #pragma unroll
            for (int o=0;o<NOUT;o++) acc[o]=0.f;
            float cv[16];
            #pragma unroll
            for (int s4=0;s4<4;s4++){
                float4 c0 = ((const float4*)ctxs[0])[lane*4+s4];
                float4 c1 = ((const float4*)ctxs[1])[lane*4+s4];
                float4 c2 = ((const float4*)ctxs[2])[lane*4+s4];
                float4 c3 = ((const float4*)ctxs[3])[lane*4+s4];
                cv[s4*4+0]=c0.x+c1.x+c2.x+c3.x;
                cv[s4*4+1]=c0.y+c1.y+c2.y+c3.y;
                cv[s4*4+2]=c0.z+c1.z+c2.z+c3.z;
                cv[s4*4+3]=c0.w+c1.w+c2.w+c3.w;
            }
            #pragma unroll
            for (int dd=0;dd<16;++dd){
                int d = lane*16 + dd;
                const float* w0p = fcW + (size_t)d*NOUT;
                const float* w1p = fcW + (size_t)(d+HH)*NOUT;
                float hv=q[dd], cvv=cv[dd];
                #pragma unroll
                for (int o=0;o<NOUT;o++) acc[o] = fmaf(hv, w0p[o], fmaf(cvv, w1p[o], acc[o]));
            }
            #pragma unroll
            for (int o=0;o<NOUT;o++){
                #pragma unroll
                for (int m=1;m<64;m<<=1) acc[o] += __shfl_xor(acc[o], m);
            }
            float vout = 0.f;
            #pragma unroll
            for (int o=0;o<NOUT;o++) if (lane == o) vout = acc[o] + fcb[o];
            if (lane < NOUT) out[((size_t)b*TT + 99)*NOUT + lane] = vout;
        }
    } else {
        for (int i=0;i<TT;++i) gridbar(bar + (size_t)i*256, wg & 15, 256);
    }
}

extern "C" void kernel_launch(void* const* d_in, const int* in_sizes, int n_in,
                              void* d_out, int out_size, void* d_ws, size_t ws_size,
                              hipStream_t stream){
    (void)in_sizes; (void)n_in; (void)out_size; (void)ws_size;
    const float* x     = (const float*)d_in[0];
    const float* encW  = (const float*)d_in[1];
    const float* encU  = (const float*)d_in[2];
    const float* encb  = (const float*)d_in[3];
    const float* scale = (const float*)d_in[4];
    const float* emb   = (const float*)d_in[5];
    const float* decW  = (const float*)d_in[6];
    const float* decU  = (const float*)d_in[7];
    const float* decb  = (const float*)d_in[8];
    const float* fcW   = (const float*)d_in[9];
    const float* fcb   = (const float*)d_in[10];
    float* out = (float*)d_out;
    float* ws  = (float*)d_ws;

    // total: 32,985,088 floats + 70,400 ints ~= 132.2 MB (< round-2-proven 133.0 MB)
    float* MXT   = ws;                        // 19,660,800
    float* encUt = MXT   + 19660800;          // 3,145,728
    float* decUt = encUt + 3145728;           // 3,145,728
    float* hpe   = decUt + 3145728;           // 6,553,600
    float* Edec  = hpe   + 6553600;           // 86,016
    float* hT    = Edec  + 86016;             // 2*65,536 ping-pong [k][b]
    float* hdT   = hT    + 131072;            // 2*65,536 ping-pong [k][b]
    float* hdl   = hdT   + 131072;            // 2*65,536 ping-pong [b][k]
    int*   ib    = (int*)(hdl + 131072);
    int*   bar_enc = ib;                      // 100*256
    int*   bar_dec = ib + 25600;              // 100*256
    int*   flagidx = ib + 51200;              // 100*128
    int*   idx_t   = ib + 64000;              // 100*64   (total 70,400 ints)

    const float* encb1 = encb + H3;
    const float* decb1 = decb + H3;

    k_init<<<276,256,0,stream>>>(ib, 70400);
    k_transpose<<<dim3(96,32,2),256,0,stream>>>(encU, decU, encUt, decUt);
    k_edec<<<336,256,0,stream>>>(emb, decW, decb, Edec);
    k_mxgemm<<<dim3(48,100),256,0,stream>>>(x, encW, encb, MXT);
    k_enc<<<256,256,0,stream>>>(MXT, encUt, encb1, hpe, hT, bar_enc);
    k_dec<<<256,512,0,stream>>>(hpe, decUt, decb1, Edec, scale, fcW, fcb,
                                hdT, hdl, out, idx_t, bar_dec, flagidx);
}

// Round 8
// 10900.599 us; speedup vs baseline: 1.4620x; 1.0149x over previous
//
#include <hip/hip_runtime.h>

#define TT 100
#define HH 1024
#define H3 3072
#define NOUT 28

#define AGENT __HIP_MEMORY_SCOPE_AGENT
#define WGRP  __HIP_MEMORY_SCOPE_WORKGROUP
#define SPIN_CAP (1u<<20)

__device__ __forceinline__ float frcp_(float x){ return __builtin_amdgcn_rcpf(x); }
__device__ __forceinline__ float fsig_(float x){ return frcp_(1.0f + __expf(-x)); }
__device__ __forceinline__ float ftanh_(float x){ return 1.0f - 2.0f*frcp_(__expf(2.0f*x) + 1.0f); }

__device__ __forceinline__ unsigned long long aload8(const unsigned long long* p){
    return __hip_atomic_load(p, __ATOMIC_RELAXED, AGENT);
}
__device__ __forceinline__ unsigned aload4(const int* p){
    return (unsigned)__hip_atomic_load(p, __ATOMIC_RELAXED, AGENT);
}

// grid barrier: 16 padded sub-counters per slot (slot stride = 256 ints), relaxed only.
// Data visibility: agent-scope atomic stores to fresh per-slot buffers (round-4-proven).
__device__ __forceinline__ void gridbar(int* slot, int sub, int target){
    __syncthreads();   // drains vmcnt -> stores complete before arrival
    if (threadIdx.x == 0){
        __hip_atomic_fetch_add(slot + sub*16, 1, __ATOMIC_RELAXED, AGENT);
        unsigned gy = 0; int s;
        do {
            s = 0;
            #pragma unroll
            for (int c=0;c<16;c++) s += __hip_atomic_load(slot + c*16, __ATOMIC_RELAXED, AGENT);
            if (s < target){ if (++gy > SPIN_CAP) break; __builtin_amdgcn_s_sleep(1); }
        } while (s < target);
    }
    __syncthreads();
}

// barrier among the 4 matmul waves only (LDS counter, monotonic target), capped
__device__ __forceinline__ void wbar4(int* c, int tgt){
    asm volatile("s_waitcnt lgkmcnt(0)" ::: "memory");
    if ((threadIdx.x & 63) == 0) __hip_atomic_fetch_add(c, 1, __ATOMIC_RELAXED, WGRP);
    unsigned gy = 0;
    while (__hip_atomic_load(c, __ATOMIC_RELAXED, WGRP) < tgt){ if (++gy > SPIN_CAP) break; }
    asm volatile("" ::: "memory");
}

// ---------------- init: zero control ints ----------------
__global__ void k_init(int* ib, int n){
    int g = blockIdx.x*256 + threadIdx.x;
    if (g < n) ib[g] = 0;
}

// ---------------- transpose U [1024][3072] -> Ut [3072][1024] ----------------
__global__ __launch_bounds__(256) void k_transpose(const float* __restrict__ U0,
                                                   const float* __restrict__ U1,
                                                   float* __restrict__ T0,
                                                   float* __restrict__ T1){
    const float* U = blockIdx.z ? U1 : U0;
    float*       T = blockIdx.z ? T1 : T0;
    __shared__ float tile[32][33];
    int tx = threadIdx.x & 31, ty = threadIdx.x >> 5;
    int j0 = blockIdx.x*32, k0 = blockIdx.y*32;
    #pragma unroll
    for (int q=0;q<4;q++){
        int kr = ty + q*8;
        tile[kr][tx] = U[(size_t)(k0+kr)*H3 + j0 + tx];
    }
    __syncthreads();
    #pragma unroll
    for (int q=0;q<4;q++){
        int jr = ty + q*8;
        T[(size_t)(j0+jr)*HH + k0 + tx] = tile[tx][jr];
    }
}

// ---------------- Edec[28][3072] = emb @ decW + decb[0] ----------------
__global__ __launch_bounds__(256) void k_edec(const float* __restrict__ emb,
                                              const float* __restrict__ W,
                                              const float* __restrict__ b0,
                                              float* __restrict__ E){
    int gid = blockIdx.x*256 + threadIdx.x;   // 28*3072 = 86016
    int v = gid / H3, j = gid - v*H3;
    float acc = b0[j];
    const float* er = emb + (size_t)v*HH;
    #pragma unroll 4
    for (int k=0;k<HH;k++) acc = fmaf(er[k], W[(size_t)k*H3 + j], acc);
    E[gid] = acc;
}

// ---------------- MXT[t][col][b] = (x2d @ encW + encb[0]) transposed ----------------
__global__ __launch_bounds__(256) void k_mxgemm(const float* __restrict__ A,
                                                const float* __restrict__ W,
                                                const float* __restrict__ b0,
                                                float* __restrict__ MXT){
    __shared__ float aT[32*68];
    __shared__ float bL[32*68];
    int tid = threadIdx.x;
    int row0 = blockIdx.y*64, col0 = blockIdx.x*64;
    int arow = tid>>2, acs = (tid&3)*4;
    int bk   = tid>>3, bcs = (tid&7)*4;
    int ty = tid>>4, tx = tid&15;
    float acc[4][4] = {};
    for (int kk=0; kk<HH; kk+=32){
        #pragma unroll
        for (int i=0;i<2;i++){
            int c = acs + i*16;
            float4 v = *(const float4*)(A + (size_t)(row0+arow)*HH + kk + c);
            aT[(c+0)*68 + arow] = v.x; aT[(c+1)*68 + arow] = v.y;
            aT[(c+2)*68 + arow] = v.z; aT[(c+3)*68 + arow] = v.w;
        }
        #pragma unroll
        for (int i=0;i<2;i++){
            int c = bcs + i*32;
            float4 v = *(const float4*)(W + (size_t)(kk+bk)*H3 + col0 + c);
            *(float4*)(bL + bk*68 + c) = v;
        }
        __syncthreads();
        #pragma unroll
        for (int k=0;k<32;k++){
            float4 a4 = *(const float4*)(aT + k*68 + ty*4);
            float4 b4 = *(const float4*)(bL + k*68 + tx*4);
            acc[0][0]=fmaf(a4.x,b4.x,acc[0][0]); acc[0][1]=fmaf(a4.x,b4.y,acc[0][1]);
            acc[0][2]=fmaf(a4.x,b4.z,acc[0][2]); acc[0][3]=fmaf(a4.x,b4.w,acc[0][3]);
            acc[1][0]=fmaf(a4.y,b4.x,acc[1][0]); acc[1][1]=fmaf(a4.y,b4.y,acc[1][1]);
            acc[1][2]=fmaf(a4.y,b4.z,acc[1][2]); acc[1][3]=fmaf(a4.y,b4.w,acc[1][3]);
            acc[2][0]=fmaf(a4.z,b4.x,acc[2][0]); acc[2][1]=fmaf(a4.z,b4.y,acc[2][1]);
            acc[2][2]=fmaf(a4.z,b4.z,acc[2][2]); acc[2][3]=fmaf(a4.z,b4.w,acc[2][3]);
            acc[3][0]=fmaf(a4.w,b4.x,acc[3][0]); acc[3][1]=fmaf(a4.w,b4.y,acc[3][1]);
            acc[3][2]=fmaf(a4.w,b4.z,acc[3][2]); acc[3][3]=fmaf(a4.w,b4.w,acc[3][3]);
        }
        __syncthreads();
    }
    float4 bb = *(const float4*)(b0 + col0 + tx*4);
    #pragma unroll
    for (int i=0;i<4;i++){
        int r = row0 + ty*4 + i;
        int bq = r / 100; int tq = r - bq*100;
        float v0 = acc[i][0] + bb.x, v1 = acc[i][1] + bb.y;
        float v2 = acc[i][2] + bb.z, v3 = acc[i][3] + bb.w;
        float* dst = MXT + ((size_t)tq*H3 + col0 + tx*4)*64 + bq;
        dst[0]   = v0; dst[64]  = v1; dst[128] = v2; dst[192] = v3;
    }
}

// ---------------- persistent encoder: 256 WGs x 256 thr ----------------
// hT = ping-pong [2][1024][64]; staged to LDS via agent-scope 8B atomic loads
__global__ __launch_bounds__(256) void k_enc(const float* __restrict__ MXT,
                                             const float* __restrict__ Ut,
                                             const float* __restrict__ b1,
                                             float* __restrict__ hpe,
                                             float* __restrict__ hT,
                                             int* __restrict__ bar){
    __shared__ float hs[2][16384];
    int tid = threadIdx.x, lane = tid & 63;
    int wg = blockIdx.x;
    int sub = wg & 15;
    int cu = __builtin_amdgcn_readfirstlane(wg*4 + (tid>>6));
    const float* Uz = Ut + (size_t)cu*HH;
    const float* Ur = Uz + (size_t)HH*HH;
    const float* Uh = Ur + (size_t)HH*HH;
    float bz = b1[cu], br = b1[cu+HH], bh = b1[cu+2*HH];
    for (int t=0; t<TT; ++t){
        int cur = t & 1;
        const float* mx = MXT + (size_t)t*H3*64;
        float xz = mx[(size_t)cu*64 + lane];
        float xr = mx[(size_t)(cu+HH)*64 + lane];
        float xh = mx[(size_t)(cu+2*HH)*64 + lane];
        float az=0.f, ar=0.f, ah=0.f, hp=0.f;
        if (t > 0){
            const unsigned long long* g8 = (const unsigned long long*)(hT + (size_t)cur*65536);
            unsigned long long sv[32];
            #pragma unroll
            for (int s=0;s<32;s++) sv[s] = aload8(g8 + s*256 + tid);
            #pragma unroll
            for (int s=0;s<32;s++) ((unsigned long long*)hs[0])[s*256 + tid] = sv[s];
            __syncthreads();
            for (int q=0;q<4;++q){
                if (q<3){
                    #pragma unroll
                    for (int s=0;s<32;s++) sv[s] = aload8(g8 + (q+1)*8192 + s*256 + tid);
                }
                const float* hb = hs[q&1];
                const float* Uzq = Uz + q*256;
                const float* Urq = Ur + q*256;
                const float* Uhq = Uh + q*256;
                #pragma unroll 8
                for (int k=0;k<256;++k){
                    float h = hb[k*64 + lane];
                    az = fmaf(h, Uzq[k], az);
                    ar = fmaf(h, Urq[k], ar);
                    ah = fmaf(h, Uhq[k], ah);
                }
                if ((cu>>8) == q) hp = hb[(cu&255)*64 + lane];
                if (q<3){
                    #pragma unroll
                    for (int s=0;s<32;s++) ((unsigned long long*)hs[(q+1)&1])[s*256 + tid] = sv[s];
                }
                __syncthreads();
            }
        }
        float z  = fsig_(xz + az + bz);
        float r  = fsig_(xr + ar + br);
        float hh = ftanh_(xh + r*(ah + bh));
        float hnew = z*hp + (1.f - z)*hh;
        __hip_atomic_store(hT + (size_t)(cur^1)*65536 + cu*64 + lane, hnew, __ATOMIC_RELAXED, AGENT);
        hpe[((size_t)lane*TT + t)*HH + cu] = hnew;
        gridbar(bar + (size_t)t*256, sub, 256);
    }
}

// ---------------- persistent decoder: 256 WGs x 512 thr ----------------
// waves 0-3: GRU matmul (unit = wg*4+wave, lane = batch); waves 4-7 on wg<64: attention team b=wg
__global__ __launch_bounds__(512) void k_dec(const float* __restrict__ hpe,
                                             const float* __restrict__ Ut,
                                             const float* __restrict__ b1,
                                             const float* __restrict__ Edec,
                                             const float* __restrict__ scale,
                                             const float* __restrict__ fcW,
                                             const float* __restrict__ fcb,
                                             float* __restrict__ hdT,
                                             float* __restrict__ hdl,
                                             float* __restrict__ out,
                                             int* __restrict__ idx_t,
                                             int* __restrict__ bar,
                                             int* __restrict__ flagidx){
    __shared__ float hs[2][16384];
    __shared__ float ctxs[4][1024];
    __shared__ float m_s[4], S_s[4];
    __shared__ int c_a, c_fc, go, cstg;
    int tid = threadIdx.x, wg = blockIdx.x;
    if (tid == 0){ c_a=0; c_fc=0; go=0; cstg=0; }
    __syncthreads();

    if (tid < 256){
        // ============ matmul role ============
        int lane = tid & 63;
        int sub = wg & 15;
        int cu = __builtin_amdgcn_readfirstlane(wg*4 + (tid>>6));
        const float* Uz = Ut + (size_t)cu*HH;
        const float* Ur = Uz + (size_t)HH*HH;
        const float* Uh = Ur + (size_t)HH*HH;
        float bz = b1[cu], br = b1[cu+HH], bh = b1[cu+2*HH];
        int stgt = 0;
        for (int i=0; i<TT; ++i){
            int cur = i & 1;
            float az=0.f, ar=0.f, ah=0.f, hp=0.f;
            if (i > 0){
                const unsigned long long* g8 = (const unsigned long long*)(hdT + (size_t)cur*65536);
                unsigned long long sv[32];
                #pragma unroll
                for (int s=0;s<32;s++) sv[s] = aload8(g8 + s*256 + tid);
                #pragma unroll
                for (int s=0;s<32;s++) ((unsigned long long*)hs[0])[s*256 + tid] = sv[s];
                wbar4(&cstg, stgt += 4);
                for (int q=0;q<4;++q){
                    if (q<3){
                        #pragma unroll
                        for (int s=0;s<32;s++) sv[s] = aload8(g8 + (q+1)*8192 + s*256 + tid);
                    }
                    const float* hb = hs[q&1];
                    const float* Uzq = Uz + q*256;
                    const float* Urq = Ur + q*256;
                    const float* Uhq = Uh + q*256;
                    #pragma unroll 8
                    for (int k=0;k<256;++k){
                        float h = hb[k*64 + lane];
                        az = fmaf(h, Uzq[k], az);
                        ar = fmaf(h, Urq[k], ar);
                        ah = fmaf(h, Uhq[k], ah);
                    }
                    if ((cu>>8) == q) hp = hb[(cu&255)*64 + lane];
                    if (q<3){
                        #pragma unroll
                        for (int s=0;s<32;s++) ((unsigned long long*)hs[(q+1)&1])[s*256 + tid] = sv[s];
                    }
                    wbar4(&cstg, stgt += 4);
                }
            }
            // wait for idx(i): single poller + LDS broadcast
            if (tid == 0){
                unsigned gy = 0; int s;
                do {
                    s = 0;
                    #pragma unroll
                    for (int c=0;c<8;c++) s += __hip_atomic_load(flagidx + (size_t)i*128 + c*16, __ATOMIC_RELAXED, AGENT);
                    if (s < 64){ if (++gy > SPIN_CAP) break; __builtin_amdgcn_s_sleep(1); }
                } while (s < 64);
                __hip_atomic_store(&go, i+1, __ATOMIC_RELAXED, WGRP);
            }
            { unsigned gy=0; while (__hip_atomic_load(&go, __ATOMIC_RELAXED, WGRP) < i+1){ if (++gy > SPIN_CAP) break; } }
            asm volatile("" ::: "memory");
            unsigned mi = aload4(idx_t + (size_t)i*64 + lane);
            if (mi > 27u) mi = 0;
            const float* ed = Edec + (size_t)mi*H3;
            float xz = ed[cu], xr = ed[cu+HH], xh = ed[cu+2*HH];
            float z  = fsig_(xz + az + bz);
            float r  = fsig_(xr + ar + br);
            float hh = ftanh_(xh + r*(ah + bh));
            float hnew = z*hp + (1.f - z)*hh;
            __hip_atomic_store(hdT + (size_t)(cur^1)*65536 + cu*64 + lane, hnew, __ATOMIC_RELAXED, AGENT);
            __hip_atomic_store(hdl + (size_t)(cur^1)*65536 + (size_t)lane*HH + cu, hnew, __ATOMIC_RELAXED, AGENT);
            gridbar(bar + (size_t)i*256, sub, 256);
        }
    } else if (wg < 64){
        // ============ attention team for batch b = wg ============
        int t2 = tid - 256;
        int w = t2 >> 6, lane = t2 & 63, b = wg;
        float sc[16];
        #pragma unroll
        for (int s4=0;s4<4;s4++){
            float4 v = *(const float4*)(scale + lane*16 + s4*4);
            sc[s4*4+0]=v.x; sc[s4*4+1]=v.y; sc[s4*4+2]=v.z; sc[s4*4+3]=v.w;
        }
        int j0 = w*25;
        for (int i=0; i<TT; ++i){
            float q[16];
            if (i == 0){
                #pragma unroll
                for (int d=0;d<16;d++) q[d]=0.f;
            } else {
                const unsigned long long* hq8 = (const unsigned long long*)(hdl + (size_t)(i&1)*65536 + (size_t)b*HH) + lane*8;
                #pragma unroll
                for (int s8=0;s8<8;s8++){
                    unsigned long long v = aload8(hq8 + s8);
                    q[2*s8+0] = __uint_as_float((unsigned)v);
                    q[2*s8+1] = __uint_as_float((unsigned)(v>>32));
                }
            }
            if (w == 0){
                if (i > 0){
                    float acc[NOUT];
                    #pragma unroll
                    for (int o=0;o<NOUT;o++) acc[o]=0.f;
                    float cv[16];
                    #pragma unroll
                    for (int s4=0;s4<4;s4++){
                        float4 c0 = ((const float4*)ctxs[0])[lane*4+s4];
                        float4 c1 = ((const float4*)ctxs[1])[lane*4+s4];
                        float4 c2 = ((const float4*)ctxs[2])[lane*4+s4];
                        float4 c3 = ((const float4*)ctxs[3])[lane*4+s4];
                        cv[s4*4+0]=c0.x+c1.x+c2.x+c3.x;
                        cv[s4*4+1]=c0.y+c1.y+c2.y+c3.y;
                        cv[s4*4+2]=c0.z+c1.z+c2.z+c3.z;
                        cv[s4*4+3]=c0.w+c1.w+c2.w+c3.w;
                    }
                    #pragma unroll
                    for (int dd=0;dd<16;++dd){
                        int d = lane*16 + dd;
                        const float* w0p = fcW + (size_t)d*NOUT;
                        const float* w1p = fcW + (size_t)(d+HH)*NOUT;
                        float hv=q[dd], cvv=cv[dd];
                        #pragma unroll
                        for (int o=0;o<NOUT;o++) acc[o] = fmaf(hv, w0p[o], fmaf(cvv, w1p[o], acc[o]));
                    }
                    #pragma unroll
                    for (int o=0;o<NOUT;o++){
                        #pragma unroll
                        for (int m=1;m<64;m<<=1) acc[o] += __shfl_xor(acc[o], m);
                    }
                    float bv=-3.0e38f; int bi=0;
                    #pragma unroll
                    for (int o=0;o<NOUT;o++){
                        float p = acc[o] + fcb[o];
                        acc[o] = p;
                        if (p > bv){ bv = p; bi = o; }
                    }
                    float vout = 0.f;
                    #pragma unroll
                    for (int o=0;o<NOUT;o++) if (lane == o) vout = acc[o];
                    if (lane < NOUT) out[((size_t)b*TT + (i-1))*NOUT + lane] = vout;
                    if (lane == 0){
                        __hip_atomic_store(idx_t + (size_t)i*64 + b, bi, __ATOMIC_RELAXED, AGENT);
                        asm volatile("s_waitcnt vmcnt(0)" ::: "memory");
                    }
                }
                if (lane == 0){
                    __hip_atomic_fetch_add(flagidx + (size_t)i*128 + (b&7)*16, 1, __ATOMIC_RELAXED, AGENT);
                    __hip_atomic_fetch_add(&c_fc, 1, __ATOMIC_RELAXED, WGRP);
                }
            }
            // ---- online-softmax single pass over this wave's 25 keys (hpe read ONCE) ----
            float m = -3.0e38f, S = 0.f;
            float a[16];
            #pragma unroll
            for (int d=0;d<16;d++) a[d]=0.f;
            for (int jj=0;jj<25;jj++){
                int j = j0 + jj;
                const float* hpj = hpe + ((size_t)b*TT + j)*HH + lane*16;
                float va[16];
                {
                    float4 v0 = *(const float4*)(hpj);
                    float4 v1 = *(const float4*)(hpj+4);
                    float4 v2 = *(const float4*)(hpj+8);
                    float4 v3 = *(const float4*)(hpj+12);
                    va[0]=v0.x;va[1]=v0.y;va[2]=v0.z;va[3]=v0.w;
                    va[4]=v1.x;va[5]=v1.y;va[6]=v1.z;va[7]=v1.w;
                    va[8]=v2.x;va[9]=v2.y;va[10]=v2.z;va[11]=v2.w;
                    va[12]=v3.x;va[13]=v3.y;va[14]=v3.z;va[15]=v3.w;
                }
                float s = 0.f;
                #pragma unroll
                for (int d=0;d<16;d++) s += sc[d]*ftanh_(q[d] + va[d]);
                #pragma unroll
                for (int mm=1;mm<64;mm<<=1) s += __shfl_xor(s, mm);
                float mn = fmaxf(m, s);
                float fold = __expf(m - mn);
                float e = __expf(s - mn);
                S = S*fold + e;
                #pragma unroll
                for (int d=0;d<16;d++) a[d] = a[d]*fold + e*va[d];
                m = mn;
            }
            if (lane == 0){ m_s[w] = m; S_s[w] = S; }
            asm volatile("s_waitcnt lgkmcnt(0)" ::: "memory");
            if (lane == 0) __hip_atomic_fetch_add(&c_a, 1, __ATOMIC_RELAXED, WGRP);
            { unsigned gy=0; while (__hip_atomic_load(&c_a, __ATOMIC_RELAXED, WGRP) < 4*(i+1)){ if (++gy > SPIN_CAP) break; } }
            asm volatile("" ::: "memory");
            float M = fmaxf(fmaxf(m_s[0],m_s[1]), fmaxf(m_s[2],m_s[3]));
            float St = S_s[0]*__expf(m_s[0]-M) + S_s[1]*__expf(m_s[1]-M)
                     + S_s[2]*__expf(m_s[2]-M) + S_s[3]*__expf(m_s[3]-M);
            float g = __expf(m - M) * frcp_(St);
            // wait until fc consumed ctxs of step i-1
            { unsigned gy=0; while (__hip_atomic_load(&c_fc, __ATOMIC_RELAXED, WGRP) < i+1){ if (++gy > SPIN_CAP) break; } }
            asm volatile("" ::: "memory");
            #pragma unroll
            for (int s4=0;s4<4;s4++){
                float4 o4;
                o4.x=a[s4*4+0]*g; o4.y=a[s4*4+1]*g;
                o4.z=a[s4*4+2]*g; o4.w=a[s4*4+3]*g;
                ((float4*)ctxs[w])[lane*4 + s4] = o4;
            }
            gridbar(bar + (size_t)i*256, wg & 15, 256);
        }
        // epilogue: p(99) = [hd(100), ctx(99)] @ fc ; hd(100) is in hdl slot 0
        if (w == 0){
            const unsigned long long* hq8 = (const unsigned long long*)(hdl + (size_t)b*HH) + lane*8;
            float q[16];
            #pragma unroll
            for (int s8=0;s8<8;s8++){
                unsigned long long v = aload8(hq8 + s8);
                q[2*s8+0] = __uint_as_float((unsigned)v);
                q[2*s8+1] = __uint_as_float((unsigned)(v>>32));
            }
            float acc[NOUT];
            #pragma unroll
            for (int o=0;o<NOUT;o++) acc[o]=0.f;
            float cv[16];
            #pragma unroll
            for (int s4=0;s4<4;s4++){
                float4 c0 = ((const float4*)ctxs[0])[lane*4+s4];
                float4 c1 = ((const float4*)ctxs[1])[lane*4+s4];
                float4 c2 = ((const float4*)ctxs[2])[lane*4+s4];
                float4 c3 = ((const float4*)ctxs[3])[lane*4+s4];
                cv[s4*4+0]=c0.x+c1.x+c2.x+c3.x;
                cv[s4*4+1]=c0.y+c1.y+c2.y+c3.y;
                cv[s4*4+2]=c0.z+c1.z+c2.z+c3.z;
                cv[s4*4+3]=c0.w+c1.w+c2.w+c3.w;
            }
            #pragma unroll
            for (int dd=0;dd<16;++dd){
                int d = lane*16 + dd;
                const float* w0p = fcW + (size_t)d*NOUT;
                const float* w1p = fcW + (size_t)(d+HH)*NOUT;
                float hv=q[dd], cvv=cv[dd];
                #pragma unroll
                for (int o=0;o<NOUT;o++) acc[o] = fmaf(hv, w0p[o], fmaf(cvv, w1p[o], acc[o]));
            }
            #pragma unroll
            for (int o=0;o<NOUT;o++){
                #pragma unroll
                for (int m=1;m<64;m<<=1) acc[o] += __shfl_xor(acc[o], m);
            }
            float vout = 0.f;
            #pragma unroll
            for (int o=0;o<NOUT;o++) if (lane == o) vout = acc[o] + fcb[o];
            if (lane < NOUT) out[((size_t)b*TT + 99)*NOUT + lane] = vout;
        }
    } else {
        for (int i=0;i<TT;++i) gridbar(bar + (size_t)i*256, wg & 15, 256);
    }
}

extern "C" void kernel_launch(void* const* d_in, const int* in_sizes, int n_in,
                              void* d_out, int out_size, void* d_ws, size_t ws_size,
                              hipStream_t stream){
    (void)in_sizes; (void)n_in; (void)out_size; (void)ws_size;
    const float* x     = (const float*)d_in[0];
    const float* encW  = (const float*)d_in[1];
    const float* encU  = (const float*)d_in[2];
    const float* encb  = (const float*)d_in[3];
    const float* scale = (const float*)d_in[4];
    const float* emb   = (const float*)d_in[5];
    const float* decW  = (const float*)d_in[6];
    const float* decU  = (const float*)d_in[7];
    const float* decb  = (const float*)d_in[8];
    const float* fcW   = (const float*)d_in[9];
    const float* fcb   = (const float*)d_in[10];
    float* out = (float*)d_out;
    float* ws  = (float*)d_ws;

    // ~132.2 MB total (round-4-proven footprint)
    float* MXT   = ws;                        // 19,660,800 (encoder phase only)
    float* hdT   = MXT;                       // dec overlay: 2*65,536 ping-pong [k][b]
    float* hdl   = MXT + 131072;              // dec overlay: 2*65,536 ping-pong [b][k]
    float* encUt = MXT   + 19660800;          // 3,145,728
    float* decUt = encUt + 3145728;           // 3,145,728
    float* hpe   = decUt + 3145728;           // 6,553,600
    float* Edec  = hpe   + 6553600;           // 86,016
    float* hT    = Edec  + 86016;             // 2*65,536 ping-pong [k][b] (encoder)
    int*   ib    = (int*)(hT + 131072);
    int*   bar_enc = ib;                      // 100*256
    int*   bar_dec = ib + 25600;              // 100*256
    int*   flagidx = ib + 51200;              // 100*128
    int*   idx_t   = ib + 64000;              // 100*64   (total 70,400 ints)

    const float* encb1 = encb + H3;
    const float* decb1 = decb + H3;

    k_init<<<276,256,0,stream>>>(ib, 70400);
    k_transpose<<<dim3(96,32,2),256,0,stream>>>(encU, decU, encUt, decUt);
    k_edec<<<336,256,0,stream>>>(emb, decW, decb, Edec);
    k_mxgemm<<<dim3(48,100),256,0,stream>>>(x, encW, encb, MXT);
    k_enc<<<256,256,0,stream>>>(MXT, encUt, encb1, hpe, hT, bar_enc);
    k_dec<<<256,512,0,stream>>>(hpe, decUt, decb1, Edec, scale, fcW, fcb,
                                hdT, hdl, out, idx_t, bar_dec, flagidx);
}